// Round 9
// baseline (6223.151 us; speedup 1.0000x reference)
//
#include <hip/hip_runtime.h>

// ---------------------------------------------------------------------------
// DualMemoryLayer (entmax1.5 dual-memory scan), MI355X / gfx950
// R9 = R8 structure with the matvec h-broadcast moved to the VALU:
//   - R8's wave-uniform ds_read_b128 "broadcast" caused 6.7e7 bank conflicts
//     (uniform b128 does NOT broadcast freely; only 4B words do).
//   - Now: hreg = h_full[seg*64+lane] (one stride-1 b32/thread), then
//     v_readlane(hreg, j) per column -> SGPR broadcast, VALU fma.
//     Matvec LDS traffic: 256KB -> 4KB per WG-step.
// Kept from R8 (verified): tape double-buffer + read-from-old identity
//   r = sum(pa*(1-pb))*tape_old + (sum pa*pb)*wvv, deferred update halves,
//   fused single poll, stamped 8B relaxed-agent exchange (R4/R6-verified).
// ---------------------------------------------------------------------------

#define BB 8
#define TT 1024
#define DD 512
#define NS 32
#define KW 8            // workgroups per batch
#define SLOTS 1288      // 1024 vector slots + 8*33 partial slots

static constexpr float SCALE = 0.044194173824159216f; // 1/sqrt(512)

__device__ __forceinline__ float siluf(float v) { return v / (1.0f + __expf(-v)); }

// ---- cross-lane helpers ----------------------------------------------------
template <int CTRL>
__device__ __forceinline__ float dpp_add(float x) {
  int xi = __builtin_bit_cast(int, x);
  int yi = __builtin_amdgcn_update_dpp(0, xi, CTRL, 0xF, 0xF, false);
  return x + __builtin_bit_cast(float, yi);
}
template <int PAT>
__device__ __forceinline__ float swz_add(float x) {
  int yi = __builtin_amdgcn_ds_swizzle(__builtin_bit_cast(int, x), PAT);
  return x + __builtin_bit_cast(float, yi);
}
// value from lane^J within 32-lane segments; DPP (VALU pipe) for J=1,2
template <int J>
__device__ __forceinline__ float xlane(float x) {
  if constexpr (J == 1) {
    int yi = __builtin_amdgcn_update_dpp(0, __builtin_bit_cast(int, x), 0xB1, 0xF, 0xF, false);
    return __builtin_bit_cast(float, yi);
  } else if constexpr (J == 2) {
    int yi = __builtin_amdgcn_update_dpp(0, __builtin_bit_cast(int, x), 0x4E, 0xF, 0xF, false);
    return __builtin_bit_cast(float, yi);
  } else {
    int yi = __builtin_amdgcn_ds_swizzle(__builtin_bit_cast(int, x), (J << 10) | 0x1F);
    return __builtin_bit_cast(float, yi);
  }
}
// broadcast of lane j's value (uniform) via readlane
__device__ __forceinline__ float rdlane(float x, int j) {
  return __builtin_bit_cast(float, __builtin_amdgcn_readlane(__builtin_bit_cast(int, x), j));
}
// sum over each 32-lane half; every lane of the half gets the sum
__device__ __forceinline__ float reduce32(float x) {
  x = dpp_add<0x121>(x);
  x = dpp_add<0x122>(x);
  x = dpp_add<0x124>(x);
  x = dpp_add<0x128>(x);
  return swz_add<0x401F>(x); // lane ^= 16
}

// ---- exact 1.5-entmax over 32 values, one per lane (width-32 segments) -----
__device__ __forceinline__ float entmax32(float z, int l32) {
  float x = 0.5f * z;
  float m = x;
  m = fmaxf(m, xlane<1>(m));  m = fmaxf(m, xlane<2>(m));
  m = fmaxf(m, xlane<4>(m));  m = fmaxf(m, xlane<8>(m));
  m = fmaxf(m, xlane<16>(m));
  x -= m;
  float s = x; // bitonic sort descending
#define XST(K, J) { float y = xlane<J>(s); bool up = (((l32 & K) == 0) ^ ((l32 & J) == 0)); s = up ? fminf(s, y) : fmaxf(s, y); }
  XST(2, 1)
  XST(4, 2)  XST(4, 1)
  XST(8, 4)  XST(8, 2)  XST(8, 1)
  XST(16, 8) XST(16, 4) XST(16, 2) XST(16, 1)
  XST(32, 16) XST(32, 8) XST(32, 4) XST(32, 2) XST(32, 1)
#undef XST
  float cs = s, cq = s * s; // inclusive prefix sums
  #pragma unroll
  for (int d = 1; d < 32; d <<= 1) {
    float ts = __shfl_up(cs, d, 32);
    float tq = __shfl_up(cq, d, 32);
    if (l32 >= d) { cs += ts; cq += tq; }
  }
  float kf    = (float)(l32 + 1);
  float mean  = cs / kf;
  float msq   = cq / kf;
  float ssv   = kf * (msq - mean * mean);
  float delta = (1.0f - ssv) / kf;
  float tau   = mean - sqrtf(fmaxf(delta, 0.0f));
  unsigned long long mask = __ballot(tau <= s);
  int support = __popcll(mask & 0xFFFFFFFFull) - 1;
  float tau_star = __shfl(tau, support, 32);
  float p = fmaxf(x - tau_star, 0.0f);
  return p * p;
}

// ---- stamped exchange primitives (R4/R6-verified) --------------------------
__device__ __forceinline__ void pubv(unsigned long long* p, int t, float v) {
  unsigned long long u = ((unsigned long long)(unsigned)(t + 1) << 32) |
                         (unsigned long long)__builtin_bit_cast(unsigned, v);
  __hip_atomic_store(p, u, __ATOMIC_RELAXED, __HIP_MEMORY_SCOPE_AGENT);
}

// ---------------------------------------------------------------------------
// Tiled fp32 GEMM:  C[M,N] = A[M,K] @ B[N,K]^T
// ---------------------------------------------------------------------------
template <int MODE>
__global__ __launch_bounds__(256) void gemm_tn(const float* __restrict__ A,
                                               const float* __restrict__ Bm,
                                               float* __restrict__ C0,
                                               float* __restrict__ C1,
                                               int M, int N, int K) {
  const int bm = blockIdx.x, bn = blockIdx.y;
  const int tid = threadIdx.x;
  const int tx = tid & 15, ty = tid >> 4;
  __shared__ __align__(16) float As[16][132];
  __shared__ __align__(16) float Bs[16][132];
  float acc[8][8] = {};
  const int rowA0 = bm * 128, rowB0 = bn * 128;

  for (int k0 = 0; k0 < K; k0 += 16) {
    #pragma unroll
    for (int q = 0; q < 2; ++q) {
      int idx = tid + q * 256;
      int r   = idx >> 2;
      int kq  = (idx & 3) * 4;
      float4 a4 = *(const float4*)&A [(size_t)(rowA0 + r) * K + k0 + kq];
      float4 b4 = *(const float4*)&Bm[(size_t)(rowB0 + r) * K + k0 + kq];
      As[kq + 0][r] = a4.x; As[kq + 1][r] = a4.y; As[kq + 2][r] = a4.z; As[kq + 3][r] = a4.w;
      Bs[kq + 0][r] = b4.x; Bs[kq + 1][r] = b4.y; Bs[kq + 2][r] = b4.z; Bs[kq + 3][r] = b4.w;
    }
    __syncthreads();
    #pragma unroll
    for (int kk = 0; kk < 16; ++kk) {
      float4 a0 = *(const float4*)&As[kk][ty * 8];
      float4 a1 = *(const float4*)&As[kk][ty * 8 + 4];
      float4 b0 = *(const float4*)&Bs[kk][tx * 8];
      float4 b1 = *(const float4*)&Bs[kk][tx * 8 + 4];
      float av[8] = {a0.x, a0.y, a0.z, a0.w, a1.x, a1.y, a1.z, a1.w};
      float bv[8] = {b0.x, b0.y, b0.z, b0.w, b1.x, b1.y, b1.z, b1.w};
      #pragma unroll
      for (int i = 0; i < 8; ++i)
        #pragma unroll
        for (int j = 0; j < 8; ++j) acc[i][j] = fmaf(av[i], bv[j], acc[i][j]);
    }
    __syncthreads();
  }
  #pragma unroll
  for (int i = 0; i < 8; ++i) {
    int gr = rowA0 + ty * 8 + i;
    #pragma unroll
    for (int j = 0; j < 8; ++j) {
      int gc = rowB0 + tx * 8 + j;
      float v = acc[i][j];
      if (MODE == 0) {
        float sv = siluf(v);
        if (gc < 512) C0[(size_t)gr * 512 + gc]         = sv;
        else          C1[(size_t)gr * 512 + (gc - 512)] = sv;
      } else {
        C0[(size_t)gr * N + gc] = v;
      }
    }
  }
}

// ---------------------------------------------------------------------------
// Persistent scan.  WG (b = blk&7, g = blk>>3), 1024 threads.
// Thread (seg = tid>>7, row = tid&127): weights = fused row (g*64+row for Wh
// if row<64, else Ww row g*64+row-64), cols [seg*64, seg*64+64).
// seg is wave-uniform -> h broadcast via v_readlane (VALU), no LDS traffic.
// ---------------------------------------------------------------------------
__global__ __launch_bounds__(1024) void scan_kernel(
    const float* __restrict__ Wh, const float* __restrict__ Ww,
    const float* __restrict__ bh, const float* __restrict__ XW,
    const float* __restrict__ SZ, float* __restrict__ Y,
    unsigned long long* __restrict__ Pp,  // [2][BB][SLOTS]
    float* __restrict__ outTape, float* __restrict__ outWork) {
  const int tid  = threadIdx.x;
  const int wv   = tid >> 6, lane = tid & 63;
  const int b    = blockIdx.x & 7, g = blockIdx.x >> 3;
  const int l32  = lane & 31;
  const int seg  = tid >> 7;        // 0..7: column chunk (wave-uniform)
  const int row  = tid & 127;       // 0..127: fused local row

  __shared__ float tapeA[NS][DD];   // tape double buffer
  __shared__ float tapeB[NS][DD];
  __shared__ float h_full[DD], hpC[DD], wvvC[DD];
  __shared__ float Wpart[8][128];   // matvec seg-partials (stride-1 access)
  __shared__ float hp_loc[64], wv_loc[64];
  __shared__ float ws_arr[NS], q1part[KW * NS], q2part[KW];
  __shared__ float bArr[NS], cArr[NS];
  __shared__ float sSh;

  // stationary weights: 64 floats, contiguous cols seg*64..seg*64+63
  float w[64];
  {
    const float* src = (row < 64) ? (Wh + (size_t)(g * 64 + row) * DD + seg * 64)
                                  : (Ww + (size_t)(g * 64 + row - 64) * DD + seg * 64);
    #pragma unroll
    for (int q = 0; q < 16; ++q) {
      float4 v4 = *(const float4*)(src + 4 * q);
      w[4*q+0] = v4.x; w[4*q+1] = v4.y; w[4*q+2] = v4.z; w[4*q+3] = v4.w;
    }
  }
  const float bhr = (tid < 64) ? bh[g * 64 + tid] : 0.f;
  for (int e = tid; e < NS * DD; e += 1024) {
    ((float*)tapeA)[e] = 0.f;
    ((float*)tapeB)[e] = 0.f;
  }
  if (tid < DD) h_full[tid] = 0.f;
  __syncthreads();

  for (int t = 0; t <= TT; ++t) {
    float (*cur)[DD] = (t & 1) ? tapeB : tapeA;   // tape_{t-1}
    float (*nxt)[DD] = (t & 1) ? tapeA : tapeB;   // tape_t (written this step)
    unsigned long long* pbuf = Pp + ((size_t)(t & 1) * BB + b) * SLOTS;

    // prefetch step inputs (latency hidden under matvec)
    float xwv = 0.f;
    if (tid < 64 && t < TT) xwv = XW[((size_t)b * TT + t) * DD + g * 64 + tid];
    float szv = 0.f;
    if (t < TT && tid < DD && (tid >> 6) == g)
      szv = SZ[((size_t)b * TT + t) * DD + tid];

    // (A) matvec seg-partial: one b32/thread, then VALU readlane broadcast
    {
      float hreg = h_full[seg * 64 + lane];   // stride-1, conflict-free
      float a0 = 0.f, a1 = 0.f, a2 = 0.f, a3 = 0.f;
      #pragma unroll
      for (int j = 0; j < 64; j += 4) {
        a0 = fmaf(w[j + 0], rdlane(hreg, j + 0), a0);
        a1 = fmaf(w[j + 1], rdlane(hreg, j + 1), a1);
        a2 = fmaf(w[j + 2], rdlane(hreg, j + 2), a2);
        a3 = fmaf(w[j + 3], rdlane(hreg, j + 3), a3);
      }
      Wpart[seg][row] = (a0 + a1) + (a2 + a3);
    }
    __syncthreads();  // SYNC_A

    // (B) tid<128: combine 8 seg-partials, finalize, publish vector slots
    if (tid < 128) {
      float s = 0.f;
      #pragma unroll
      for (int k = 0; k < 8; ++k) s += Wpart[k][tid];
      float hv = (tid < 64) ? (s + xwv + bhr) : s;
      if (tid < 64) hp_loc[tid] = hv; else wv_loc[tid - 64] = hv;
      pubv(&pbuf[g * 128 + tid], t, hv);
    }
    __syncthreads();  // SYNC1: hp_loc / wv_loc ready

    // (C) q1/q2 partial dots over own d-slice -> publish; then ws full dot
    {
      int n = wv * 2 + (lane >> 5);
      float s1 = fmaf(cur[n][g * 64 + 2 * l32], hp_loc[2 * l32],
                      cur[n][g * 64 + 2 * l32 + 1] * hp_loc[2 * l32 + 1]);
      s1 = reduce32(s1);
      if (l32 == 0) pubv(&pbuf[1024 + g * 33 + n], t, s1);
      if (wv == 0) {
        float s2 = fmaf(wv_loc[l32], hp_loc[l32],
                        wv_loc[l32 + 32] * hp_loc[l32 + 32]);
        s2 = reduce32(s2);
        if (lane == 0) pubv(&pbuf[1024 + g * 33 + 32], t, s2);
      }
      float sw = 0.f;
      #pragma unroll
      for (int j = 0; j < 16; ++j)
        sw = fmaf(cur[n][l32 + 32 * j], h_full[l32 + 32 * j], sw);
      sw = reduce32(sw);
      if (l32 == 0) ws_arr[n] = sw * SCALE;
    }
    __syncthreads();  // SYNC2: ws_arr ready

    // wave1 computes entmax(b) while everyone polls (fused double poll)
    if (wv == 1) {
      float pb = entmax32(ws_arr[l32], l32);
      if (lane < NS) bArr[lane] = pb;
    }
    {
      const unsigned want = (unsigned)(t + 1);
      const bool needB = (tid < KW * 33);
      unsigned long long uA = 0, uB = 0;
      bool okA = false, okB = !needB;
      do {
        if (!okA) {
          uA = __hip_atomic_load(&pbuf[tid], __ATOMIC_RELAXED, __HIP_MEMORY_SCOPE_AGENT);
          okA = (unsigned)(uA >> 32) == want;
        }
        if (!okB) {
          uB = __hip_atomic_load(&pbuf[1024 + tid], __ATOMIC_RELAXED, __HIP_MEMORY_SCOPE_AGENT);
          okB = (unsigned)(uB >> 32) == want;
        }
      } while (!(okA && okB));
      float vA = __builtin_bit_cast(float, (unsigned)(uA & 0xFFFFFFFFu));
      int i = tid & 127, gg = tid >> 7;
      if (i < 64) hpC[gg * 64 + i] = vA;
      else        wvvC[gg * 64 + (i - 64)] = vA;
      if (needB) {
        float vB = __builtin_bit_cast(float, (unsigned)(uB & 0xFFFFFFFFu));
        int gg2 = tid / 33, j2 = tid - gg2 * 33;
        if (j2 < 32) q1part[gg2 * 32 + j2] = vB;
        else         q2part[gg2] = vB;
      }
    }
    __syncthreads();  // SYNC3: hpC/wvvC/partials/bArr ready

    // (D) wave0: sum partials, rs, entmax(a) -> cArr, sSh
    //     waves 1-15: tape update first half (n in [0,16)), cur -> nxt
    if (wv == 0) {
      if (t < TT) {
        float q1s = 0.f, q2s = 0.f;
        #pragma unroll
        for (int k = 0; k < KW; ++k) {
          q1s += q1part[k * 32 + l32];
          q2s += q2part[k];
        }
        float pb = bArr[l32];
        float rs = SCALE * fmaf(pb, q2s - q1s, q1s);
        float pa = entmax32(rs, l32);
        if (lane < NS) cArr[lane] = pa * (1.0f - pb);
        float sv = reduce32(pa * pb);
        if (lane == 0) sSh = sv;
      }
    } else {
      for (int e = tid - 64; e < 16 * 128; e += 960) {
        int n = e >> 7, dq = (e & 127) * 4;
        float  bn = bArr[n];
        float4 tv = *(float4*)&cur[n][dq];
        float4 wq = *(const float4*)&wvvC[dq];
        tv.x = fmaf(bn, wq.x - tv.x, tv.x);
        tv.y = fmaf(bn, wq.y - tv.y, tv.y);
        tv.z = fmaf(bn, wq.z - tv.z, tv.z);
        tv.w = fmaf(bn, wq.w - tv.w, tv.w);
        *(float4*)&nxt[n][dq] = tv;
      }
    }
    __syncthreads();  // SYNC4: cArr/sSh + first-half nxt ready

    if (t == TT) {  // final: finish update, emit tape_T and h_{T-1}
      if (wv >= 8) {
        for (int e = tid - 512; e < 16 * 128; e += 512) {
          int n = 16 + (e >> 7), dq = (e & 127) * 4;
          float  bn = bArr[n];
          float4 tv = *(float4*)&cur[n][dq];
          float4 wq = *(const float4*)&wvvC[dq];
          tv.x = fmaf(bn, wq.x - tv.x, tv.x);
          tv.y = fmaf(bn, wq.y - tv.y, tv.y);
          tv.z = fmaf(bn, wq.z - tv.z, tv.z);
          tv.w = fmaf(bn, wq.w - tv.w, tv.w);
          *(float4*)&nxt[n][dq] = tv;
        }
      }
      __syncthreads();
      if (tid < DD && (tid >> 6) == g) outWork[(size_t)b * DD + tid] = h_full[tid];
      for (int e = tid; e < NS * 64; e += 1024) {
        int n = e >> 6, d = g * 64 + (e & 63);
        outTape[((size_t)b * NS + n) * DD + d] = nxt[n][d];
      }
      break;
    }

    // (E) waves 0-7: read from OLD tape via exact identity + tanh + Y + h
    //     waves 8-15: tape update second half (n in [16,32)), cur -> nxt
    if (wv < 8) {
      int d = tid;  // 0..511
      float r = 0.f;
      #pragma unroll
      for (int n = 0; n < NS; ++n) r = fmaf(cArr[n], cur[n][d], r);
      r = fmaf(sSh, wvvC[d], r);
      float hn = tanhf(hpC[d] + r);
      if ((d >> 6) == g)
        Y[((size_t)b * TT + t) * DD + d] = hn * szv;
      h_full[d] = hn;
    } else {
      for (int e = tid - 512; e < 16 * 128; e += 512) {
        int n = 16 + (e >> 7), dq = (e & 127) * 4;
        float  bn = bArr[n];
        float4 tv = *(float4*)&cur[n][dq];
        float4 wq = *(const float4*)&wvvC[dq];
        tv.x = fmaf(bn, wq.x - tv.x, tv.x);
        tv.y = fmaf(bn, wq.y - tv.y, tv.y);
        tv.z = fmaf(bn, wq.z - tv.z, tv.z);
        tv.w = fmaf(bn, wq.w - tv.w, tv.w);
        *(float4*)&nxt[n][dq] = tv;
      }
    }
    __syncthreads();  // SYNC5: h_full + full nxt ready for step t+1
  }
}

// ---------------------------------------------------------------------------
extern "C" void kernel_launch(void* const* d_in, const int* in_sizes, int n_in,
                              void* d_out, int out_size, void* d_ws, size_t ws_size,
                              hipStream_t stream) {
  (void)in_sizes; (void)n_in; (void)out_size; (void)ws_size;
  const float* x    = (const float*)d_in[0];
  const float* W_in = (const float*)d_in[1];
  const float* W_out= (const float*)d_in[2];
  const float* W_h  = (const float*)d_in[3];
  const float* W_x  = (const float*)d_in[4];
  const float* b_h  = (const float*)d_in[5];
  const float* W_wr = (const float*)d_in[6];

  float* out     = (float*)d_out;                  // [B,T,D]
  float* outTape = out + (size_t)BB * TT * DD;     // [B,NS,D]
  float* outWork = outTape + (size_t)BB * NS * DD; // [B,D]

  float* wsf  = (float*)d_ws;
  float* XP   = wsf;                               // [8192,512] (Y after scan)
  float* SZ   = XP + (size_t)BB * TT * DD;
  float* XWb  = SZ + (size_t)BB * TT * DD;
  unsigned long long* Pp = (unsigned long long*)(XWb + (size_t)BB * TT * DD);
  // Pp: [2][BB][SLOTS].  No init needed: 0xAA poison stamp never equals any
  // wanted stamp t+1 (1..1025).

  gemm_tn<0><<<dim3(64, 8), 256, 0, stream>>>(x, W_in, XP, SZ, BB * TT, 2 * DD, DD);
  gemm_tn<1><<<dim3(64, 4), 256, 0, stream>>>(XP, W_x, XWb, nullptr, BB * TT, DD, DD);
  scan_kernel<<<64, 1024, 0, stream>>>(W_h, W_wr, b_h, XWb, SZ, XP,
                                       Pp, outTape, outWork);
  gemm_tn<1><<<dim3(64, 4), 256, 0, stream>>>(XP, W_out, out, nullptr, BB * TT, DD, DD);
}

// Round 10
// 6054.144 us; speedup vs baseline: 1.0279x; 1.0279x over previous
//
#include <hip/hip_runtime.h>

// ---------------------------------------------------------------------------
// DualMemoryLayer (entmax1.5 dual-memory scan), MI355X / gfx950
// R10 = R7 base (best: 5143us scan, 0 bank conflicts) + three deltas:
//   1. backoff polling (s_sleep escalation) — deflate MALL poll congestion
//   2. fused vector+partial poll (one RT for the 264 partial-poll threads)
//   3. ws-dot moved pre-SYNC1 (needs only stable tape/h_full) -> SYNC2 gone
// Everything else (dataflow, indexing, exchange protocol) is R7 verbatim.
// ---------------------------------------------------------------------------

#define BB 8
#define TT 1024
#define DD 512
#define NS 32
#define KW 8            // workgroups per batch
#define SLOTS 1288      // 1024 vector slots + 8*33 partial slots

static constexpr float SCALE = 0.044194173824159216f; // 1/sqrt(512)

__device__ __forceinline__ float siluf(float v) { return v / (1.0f + __expf(-v)); }

// ---- cross-lane helpers ----------------------------------------------------
template <int CTRL>
__device__ __forceinline__ float dpp_add(float x) {
  int xi = __builtin_bit_cast(int, x);
  int yi = __builtin_amdgcn_update_dpp(0, xi, CTRL, 0xF, 0xF, false);
  return x + __builtin_bit_cast(float, yi);
}
template <int PAT>
__device__ __forceinline__ float swz_add(float x) {
  int yi = __builtin_amdgcn_ds_swizzle(__builtin_bit_cast(int, x), PAT);
  return x + __builtin_bit_cast(float, yi);
}
// value from lane^J within 32-lane segments; DPP (VALU pipe) for J=1,2
template <int J>
__device__ __forceinline__ float xlane(float x) {
  if constexpr (J == 1) {
    int yi = __builtin_amdgcn_update_dpp(0, __builtin_bit_cast(int, x), 0xB1, 0xF, 0xF, false);
    return __builtin_bit_cast(float, yi);
  } else if constexpr (J == 2) {
    int yi = __builtin_amdgcn_update_dpp(0, __builtin_bit_cast(int, x), 0x4E, 0xF, 0xF, false);
    return __builtin_bit_cast(float, yi);
  } else {
    int yi = __builtin_amdgcn_ds_swizzle(__builtin_bit_cast(int, x), (J << 10) | 0x1F);
    return __builtin_bit_cast(float, yi);
  }
}
// direction-proof sum within each aligned 8-lane group (every lane gets it)
__device__ __forceinline__ float reduce8(float x) {
  x = swz_add<0x041F>(x); // lane ^= 1
  x = swz_add<0x081F>(x); // lane ^= 2
  x = swz_add<0x101F>(x); // lane ^= 4
  return x;
}
// sum over each 32-lane half; every lane of the half gets the sum
__device__ __forceinline__ float reduce32(float x) {
  x = dpp_add<0x121>(x);
  x = dpp_add<0x122>(x);
  x = dpp_add<0x124>(x);
  x = dpp_add<0x128>(x);
  return swz_add<0x401F>(x); // lane ^= 16
}

// ---- exact 1.5-entmax over 32 values, one per lane (width-32 segments) -----
__device__ __forceinline__ float entmax32(float z, int l32) {
  float x = 0.5f * z;
  float m = x;
  m = fmaxf(m, xlane<1>(m));  m = fmaxf(m, xlane<2>(m));
  m = fmaxf(m, xlane<4>(m));  m = fmaxf(m, xlane<8>(m));
  m = fmaxf(m, xlane<16>(m));
  x -= m;
  float s = x; // bitonic sort descending
#define XST(K, J) { float y = xlane<J>(s); bool up = (((l32 & K) == 0) ^ ((l32 & J) == 0)); s = up ? fminf(s, y) : fmaxf(s, y); }
  XST(2, 1)
  XST(4, 2)  XST(4, 1)
  XST(8, 4)  XST(8, 2)  XST(8, 1)
  XST(16, 8) XST(16, 4) XST(16, 2) XST(16, 1)
  XST(32, 16) XST(32, 8) XST(32, 4) XST(32, 2) XST(32, 1)
#undef XST
  float cs = s, cq = s * s; // inclusive prefix sums
  #pragma unroll
  for (int d = 1; d < 32; d <<= 1) {
    float ts = __shfl_up(cs, d, 32);
    float tq = __shfl_up(cq, d, 32);
    if (l32 >= d) { cs += ts; cq += tq; }
  }
  float kf    = (float)(l32 + 1);
  float mean  = cs / kf;
  float msq   = cq / kf;
  float ssv   = kf * (msq - mean * mean);
  float delta = (1.0f - ssv) / kf;
  float tau   = mean - sqrtf(fmaxf(delta, 0.0f));
  unsigned long long mask = __ballot(tau <= s);
  int support = __popcll(mask & 0xFFFFFFFFull) - 1;
  float tau_star = __shfl(tau, support, 32);
  float p = fmaxf(x - tau_star, 0.0f);
  return p * p;
}

// ---- stamped exchange primitives (R4/R6-verified) --------------------------
__device__ __forceinline__ void pubv(unsigned long long* p, int t, float v) {
  unsigned long long u = ((unsigned long long)(unsigned)(t + 1) << 32) |
                         (unsigned long long)__builtin_bit_cast(unsigned, v);
  __hip_atomic_store(p, u, __ATOMIC_RELAXED, __HIP_MEMORY_SCOPE_AGENT);
}

// ---------------------------------------------------------------------------
// Tiled fp32 GEMM:  C[M,N] = A[M,K] @ B[N,K]^T
// ---------------------------------------------------------------------------
template <int MODE>
__global__ __launch_bounds__(256) void gemm_tn(const float* __restrict__ A,
                                               const float* __restrict__ Bm,
                                               float* __restrict__ C0,
                                               float* __restrict__ C1,
                                               int M, int N, int K) {
  const int bm = blockIdx.x, bn = blockIdx.y;
  const int tid = threadIdx.x;
  const int tx = tid & 15, ty = tid >> 4;
  __shared__ __align__(16) float As[16][132];
  __shared__ __align__(16) float Bs[16][132];
  float acc[8][8] = {};
  const int rowA0 = bm * 128, rowB0 = bn * 128;

  for (int k0 = 0; k0 < K; k0 += 16) {
    #pragma unroll
    for (int q = 0; q < 2; ++q) {
      int idx = tid + q * 256;
      int r   = idx >> 2;
      int kq  = (idx & 3) * 4;
      float4 a4 = *(const float4*)&A [(size_t)(rowA0 + r) * K + k0 + kq];
      float4 b4 = *(const float4*)&Bm[(size_t)(rowB0 + r) * K + k0 + kq];
      As[kq + 0][r] = a4.x; As[kq + 1][r] = a4.y; As[kq + 2][r] = a4.z; As[kq + 3][r] = a4.w;
      Bs[kq + 0][r] = b4.x; Bs[kq + 1][r] = b4.y; Bs[kq + 2][r] = b4.z; Bs[kq + 3][r] = b4.w;
    }
    __syncthreads();
    #pragma unroll
    for (int kk = 0; kk < 16; ++kk) {
      float4 a0 = *(const float4*)&As[kk][ty * 8];
      float4 a1 = *(const float4*)&As[kk][ty * 8 + 4];
      float4 b0 = *(const float4*)&Bs[kk][tx * 8];
      float4 b1 = *(const float4*)&Bs[kk][tx * 8 + 4];
      float av[8] = {a0.x, a0.y, a0.z, a0.w, a1.x, a1.y, a1.z, a1.w};
      float bv[8] = {b0.x, b0.y, b0.z, b0.w, b1.x, b1.y, b1.z, b1.w};
      #pragma unroll
      for (int i = 0; i < 8; ++i)
        #pragma unroll
        for (int j = 0; j < 8; ++j) acc[i][j] = fmaf(av[i], bv[j], acc[i][j]);
    }
    __syncthreads();
  }
  #pragma unroll
  for (int i = 0; i < 8; ++i) {
    int gr = rowA0 + ty * 8 + i;
    #pragma unroll
    for (int j = 0; j < 8; ++j) {
      int gc = rowB0 + tx * 8 + j;
      float v = acc[i][j];
      if (MODE == 0) {
        float sv = siluf(v);
        if (gc < 512) C0[(size_t)gr * 512 + gc]         = sv;
        else          C1[(size_t)gr * 512 + (gc - 512)] = sv;
      } else {
        C0[(size_t)gr * N + gc] = v;
      }
    }
  }
}

// ---------------------------------------------------------------------------
// Persistent scan (R7 structure).  WG (b = blk&7, g = blk>>3), 1024 threads.
// Thread (seg = tid&7, row = tid>>3): fused row g*64+row of Wh (row<64) or
// Ww (row>=64), cols [seg*64, seg*64+64) in bank-swizzled order.
// Per step: matvec+publish -> [ws dot] -> SYNC1 -> q1/q2 partial publish ->
// entmax(b) on wave1 while all do fused backoff-poll -> SYNC3 ->
// wave0 entmax(a) from summed partials || waves1-15 in-place tape update ->
// SYNC4 -> read + h=tanh(hp+read) -> SYNC5.
// ---------------------------------------------------------------------------
__global__ __launch_bounds__(1024) void scan_kernel(
    const float* __restrict__ Wh, const float* __restrict__ Ww,
    const float* __restrict__ bh, const float* __restrict__ XW,
    const float* __restrict__ SZ, float* __restrict__ Y,
    unsigned long long* __restrict__ Pp,  // [2][BB][SLOTS]
    float* __restrict__ outTape, float* __restrict__ outWork) {
  const int tid  = threadIdx.x;
  const int wv   = tid >> 6, lane = tid & 63;
  const int b    = blockIdx.x & 7, g = blockIdx.x >> 3;
  const int l32  = lane & 31;
  const int seg  = tid & 7;         // column segment (8 per row)
  const int row  = tid >> 3;        // local row 0..127 (<64: Wh, else Ww)

  __shared__ float tape[NS][DD];    // full tape replica (single buffer)
  __shared__ float h_full[DD], hpC[DD], wvvC[DD];
  __shared__ float hp_loc[64], wv_loc[64];
  __shared__ float ws_arr[NS], q1part[KW * NS], q2part[KW];
  __shared__ float bArr[NS], aArr[NS];

  // stationary weights: 64 floats = fused row, cols seg*64..seg*64+63,
  // loaded in bank-swizzled order (rotate by 4*seg floats within the segment)
  float w[64];
  {
    const float* src = (row < 64) ? (Wh + (size_t)(g * 64 + row) * DD)
                                  : (Ww + (size_t)(g * 64 + row - 64) * DD);
    #pragma unroll
    for (int q = 0; q < 16; ++q) {
      int c4 = seg * 64 + ((4 * q + 4 * seg) & 63);
      float4 v4 = *(const float4*)(src + c4);
      w[4*q+0] = v4.x; w[4*q+1] = v4.y; w[4*q+2] = v4.z; w[4*q+3] = v4.w;
    }
  }
  const float bhv = (seg == 0 && row < 64) ? bh[g * 64 + row] : 0.f;
  for (int e = tid; e < NS * DD; e += 1024) ((float*)tape)[e] = 0.f;
  if (tid < DD) h_full[tid] = 0.f;
  __syncthreads();

  for (int t = 0; t <= TT; ++t) {
    unsigned long long* pbuf = Pp + ((size_t)(t & 1) * BB + b) * SLOTS;

    // prefetch step inputs (latency hidden under matvec)
    float xwv = 0.f;
    if (seg == 0 && row < 64 && t < TT)
      xwv = XW[((size_t)b * TT + t) * DD + g * 64 + row];
    float szv = 0.f;
    if (t < TT && tid < DD && (tid >> 6) == g)
      szv = SZ[((size_t)b * TT + t) * DD + tid];

    // (A) row-slice matvec: pv = sum over my 64 cols of W[row]*h
    float pv = 0.f;
    #pragma unroll
    for (int q = 0; q < 16; ++q) {
      int c4 = seg * 64 + ((4 * q + 4 * seg) & 63);   // bank-conflict-free
      float4 h4 = *(const float4*)&h_full[c4];
      pv = fmaf(w[4*q+0], h4.x, pv);
      pv = fmaf(w[4*q+1], h4.y, pv);
      pv = fmaf(w[4*q+2], h4.z, pv);
      pv = fmaf(w[4*q+3], h4.w, pv);
    }
    pv = reduce8(pv);            // xor butterfly: every lane has the row sum
    if (seg == 0) {
      float hv = (row < 64) ? (pv + xwv + bhv) : pv;   // hp finalized
      if (row < 64) hp_loc[row] = hv; else wv_loc[row - 64] = hv;
      pubv(&pbuf[g * 128 + row], t, hv);
    }
    // [R10 delta 3] ws = tape . h_prev — needs only stable tape/h_full,
    // so it runs BEFORE SYNC1 and the old SYNC2 is eliminated.
    {
      int n = wv * 2 + (lane >> 5);
      float sw = 0.f;
      #pragma unroll
      for (int j = 0; j < 16; ++j)
        sw = fmaf(tape[n][l32 + 32 * j], h_full[l32 + 32 * j], sw);
      sw = reduce32(sw);
      if (l32 == 0) ws_arr[n] = sw * SCALE;
    }
    __syncthreads();  // SYNC1: hp_loc / wv_loc / ws_arr ready

    // (C) q1/q2 partial dots over own d-slice -> publish
    {
      int n = wv * 2 + (lane >> 5);
      float s1 = fmaf(tape[n][g * 64 + 2 * l32], hp_loc[2 * l32],
                      tape[n][g * 64 + 2 * l32 + 1] * hp_loc[2 * l32 + 1]);
      s1 = reduce32(s1);
      if (l32 == 0) pubv(&pbuf[1024 + g * 33 + n], t, s1);
      if (wv == 0) {
        float s2 = fmaf(wv_loc[l32], hp_loc[l32],
                        wv_loc[l32 + 32] * hp_loc[l32 + 32]);
        s2 = reduce32(s2);
        if (lane == 0) pubv(&pbuf[1024 + g * 33 + 32], t, s2);
      }
    }

    // wave1 computes entmax(b) first; everyone then polls
    if (wv == 1) {
      float pb = entmax32(ws_arr[l32], l32);
      if (lane < NS) bArr[lane] = pb;
    }
    // [R10 deltas 1+2] fused vector+partial poll with s_sleep backoff
    {
      const unsigned want = (unsigned)(t + 1);
      const bool needB = (tid < KW * 33);
      unsigned long long uA = 0, uB = 0;
      bool okA = false, okB = !needB;
      int spin = 0;
      for (;;) {
        if (!okA) {
          uA = __hip_atomic_load(&pbuf[tid], __ATOMIC_RELAXED, __HIP_MEMORY_SCOPE_AGENT);
          okA = (unsigned)(uA >> 32) == want;
        }
        if (!okB) {
          uB = __hip_atomic_load(&pbuf[1024 + tid], __ATOMIC_RELAXED, __HIP_MEMORY_SCOPE_AGENT);
          okB = (unsigned)(uB >> 32) == want;
        }
        if (okA && okB) break;
        if (spin == 0)      { /* immediate retry */ }
        else if (spin < 3)  __builtin_amdgcn_s_sleep(2);   // ~128 cyc
        else                __builtin_amdgcn_s_sleep(8);   // ~512 cyc
        ++spin;
      }
      float vA = __builtin_bit_cast(float, (unsigned)(uA & 0xFFFFFFFFu));
      int i = tid & 127, gg = tid >> 7;
      if (i < 64) hpC[gg * 64 + i] = vA;
      else        wvvC[gg * 64 + (i - 64)] = vA;
      if (needB) {
        float vB = __builtin_bit_cast(float, (unsigned)(uB & 0xFFFFFFFFu));
        int gg2 = tid / 33, j2 = tid - gg2 * 33;
        if (j2 < 32) q1part[gg2 * 32 + j2] = vB;
        else         q2part[gg2] = vB;
      }
    }
    __syncthreads();  // SYNC3: hpC/wvvC/partials/bArr ready

    // (D) wave0: sum partials, rs, entmax(a) -> aArr
    //     waves 1-15: in-place tape update (needs bArr + wvvC)
    if (wv == 0) {
      if (t < TT) {
        float q1s = 0.f, q2s = 0.f;
        #pragma unroll
        for (int k = 0; k < KW; ++k) {
          q1s += q1part[k * 32 + l32];
          q2s += q2part[k];
        }
        float pb = bArr[l32];
        float rs = SCALE * fmaf(pb, q2s - q1s, q1s);
        float pa = entmax32(rs, l32);
        if (lane < NS) aArr[lane] = pa;
      }
    } else {
      for (int e = tid - 64; e < NS * DD / 4; e += 960) {
        int n = e >> 7, dq = (e & 127) * 4;
        float  bn = bArr[n];
        float4 tv = *(float4*)&tape[n][dq];
        float4 wq = *(const float4*)&wvvC[dq];
        tv.x = fmaf(bn, wq.x - tv.x, tv.x);
        tv.y = fmaf(bn, wq.y - tv.y, tv.y);
        tv.z = fmaf(bn, wq.z - tv.z, tv.z);
        tv.w = fmaf(bn, wq.w - tv.w, tv.w);
        *(float4*)&tape[n][dq] = tv;
      }
    }
    __syncthreads();  // SYNC4: aArr + tape_new ready

    if (t == TT) {  // final outputs: tape_T and h_{T-1}
      if (tid < DD && (tid >> 6) == g) outWork[(size_t)b * DD + tid] = h_full[tid];
      for (int e = tid; e < NS * 64; e += 1024) {
        int n = e >> 6, d = g * 64 + (e & 63);
        outTape[((size_t)b * NS + n) * DD + d] = tape[n][d];
      }
      break;
    }

    // (E) read + h_t = tanh(hp + read);  Y for own slice
    if (tid < DD) {
      float r = 0.f;
      #pragma unroll
      for (int n = 0; n < NS; ++n) r = fmaf(aArr[n], tape[n][tid], r);
      float hn = tanhf(hpC[tid] + r);
      if ((tid >> 6) == g)
        Y[((size_t)b * TT + t) * DD + tid] = hn * szv;
      h_full[tid] = hn;
    }
    __syncthreads();  // SYNC5: h_full ready for step t+1
  }
}

// ---------------------------------------------------------------------------
extern "C" void kernel_launch(void* const* d_in, const int* in_sizes, int n_in,
                              void* d_out, int out_size, void* d_ws, size_t ws_size,
                              hipStream_t stream) {
  (void)in_sizes; (void)n_in; (void)out_size; (void)ws_size;
  const float* x    = (const float*)d_in[0];
  const float* W_in = (const float*)d_in[1];
  const float* W_out= (const float*)d_in[2];
  const float* W_h  = (const float*)d_in[3];
  const float* W_x  = (const float*)d_in[4];
  const float* b_h  = (const float*)d_in[5];
  const float* W_wr = (const float*)d_in[6];

  float* out     = (float*)d_out;                  // [B,T,D]
  float* outTape = out + (size_t)BB * TT * DD;     // [B,NS,D]
  float* outWork = outTape + (size_t)BB * NS * DD; // [B,D]

  float* wsf  = (float*)d_ws;
  float* XP   = wsf;                               // [8192,512] (Y after scan)
  float* SZ   = XP + (size_t)BB * TT * DD;
  float* XWb  = SZ + (size_t)BB * TT * DD;
  unsigned long long* Pp = (unsigned long long*)(XWb + (size_t)BB * TT * DD);
  // Pp: [2][BB][SLOTS].  No init needed: 0xAA poison stamp never equals any
  // wanted stamp t+1 (1..1025).

  gemm_tn<0><<<dim3(64, 8), 256, 0, stream>>>(x, W_in, XP, SZ, BB * TT, 2 * DD, DD);
  gemm_tn<1><<<dim3(64, 4), 256, 0, stream>>>(XP, W_x, XWb, nullptr, BB * TT, DD, DD);
  scan_kernel<<<64, 1024, 0, stream>>>(W_h, W_wr, b_h, XWb, SZ, XP,
                                       Pp, outTape, outWork);
  gemm_tn<1><<<dim3(64, 4), 256, 0, stream>>>(XP, W_out, out, nullptr, BB * TT, DD, DD);
}